// Round 10
// baseline (405.993 us; speedup 1.0000x reference)
//
#include <hip/hip_runtime.h>
#include <math.h>

#define KS 48
#define TLEN 512
#define BN 1024
#define START_S 46
#define STOP_S 47
#define NEGV -10000.0f
#define PF 8   // emission prefetch depth

typedef float v2f __attribute__((ext_vector_type(2)));

__device__ __forceinline__ float bcast_lane0(float v) {
    return __builtin_bit_cast(float, __builtin_amdgcn_readfirstlane(__builtin_bit_cast(int, v)));
}
__device__ __forceinline__ float rlane(float v, int k) {
    return __builtin_bit_cast(float, __builtin_amdgcn_readlane(__builtin_bit_cast(int, v), k));
}

// wave argmax, first-index tie-break (terminal only; validated rounds 1-7)
__device__ __forceinline__ void wargmax(float& bv, int& bi) {
    #pragma unroll
    for (int off = 32; off; off >>= 1) {
        float ov = __shfl_xor(bv, off, 64);
        int   oi = __shfl_xor(bi, off, 64);
        if (ov > bv || (ov == bv && oi < bi)) { bv = ov; bi = oi; }
    }
}

// grid = 2048, 1-wave blocks (concurrent structure).
// ROUND-17: R9 confirmed the compare-chain theory (272us kernel). Remaining
// anomaly: vit max-only scan ~1078cy/step despite being lighter than fwd
// (586cy/step). Discriminating experiment that can also win: move vit's
// exchange off the DS pipe (fwd keeps LDS) onto the VALU via R1's proven
// readlane broadcast — 48 v_readlane + 48 v_add(sgpr,vgpr) + max tree,
// zero compares, zero DS ops. Halves per-CU DS demand during the overlapped
// phase (8 waves/CU x 13 DS/step was ~70% of the DS pipe) and the readlane
// chain (~300-400cy) may undercut the LDS round-trip. fp max exact -> any
// tree bit-exact; adds are the identical fl(vit_p + T[n,p]) values.
// Everything else verbatim R9 (absmax 0.0 x9).
__global__ __launch_bounds__(64) void crf17(
    const float* __restrict__ feats,   // [B, T, K]
    const float* __restrict__ trans,   // [K, K]  trans[next, prev]
    const int*   __restrict__ tags,    // [B, T]
    float*       __restrict__ out,     // [B] nll | [B] path_score | [B*T] paths
    float*       __restrict__ vw_g)    // [B, T, K] pre-emission max rows B_t
{
    const int lane = threadIdx.x;
    const bool act = lane < KS;

    __shared__ __align__(16) unsigned char pool[16384];
    float* xbuf = (float*)pool;                    // fwd scan: 256B exchange

    if (blockIdx.x < BN) {
        // ================= FORWARD (verbatim, absmax 0.0 for 9 rounds) =========
        const int b = blockIdx.x;
        const float* fb = feats + (size_t)b * TLEN * KS;
        const int*   tb = tags + (size_t)b * TLEN;

        float Erow[KS];   // exp(masked trans[next=lane][p]); exp(-10000)==0
        {
            const float* tr = trans + (act ? lane : 0) * KS;
            #pragma unroll
            for (int p = 0; p < KS; ++p) {
                float tv = act ? tr[p] : NEGV;
                if (lane == START_S) tv = NEGV;
                if (p == STOP_S)     tv = NEGV;
                Erow[p] = __expf(tv);
            }
        }
        float tstart = act ? trans[lane * KS + START_S] : NEGV;
        if (lane == START_S) tstart = NEGV;

        float alpha = (act ? fb[lane] : -INFINITY) + tstart;   // t=0 peeled, exact

        auto fstep = [&](float emv) {
            float s  = bcast_lane0(alpha);       // lane-0 alpha finite: valid shift
            float ue = __expf(alpha - s);        // -inf lanes -> 0
            xbuf[lane] = ue;                     // same-wave in-order LDS: no barrier
            const float4* uu = (const float4*)xbuf;
            v2f acc0 = {0.f, 0.f}, acc1 = {0.f, 0.f};
            #pragma unroll
            for (int g = 0; g < KS / 4; ++g) {
                float4 u = uu[g];
                v2f ua = {u.x, u.y}, ub = {u.z, u.w};
                v2f ea = {Erow[4 * g + 0], Erow[4 * g + 1]};
                v2f eb = {Erow[4 * g + 2], Erow[4 * g + 3]};
                acc0 = __builtin_elementwise_fma(ua, ea, acc0);
                acc1 = __builtin_elementwise_fma(ub, eb, acc1);
            }
            alpha = emv + s + __logf((acc0.x + acc0.y) + (acc1.x + acc1.y));
        };

        float em[PF];
        #pragma unroll
        for (int j = 0; j < PF; ++j)
            em[j] = act ? fb[(1 + j) * KS + lane] : -INFINITY;
        for (int c = 0; c < 63; ++c) {
            const int t0 = 1 + c * PF;
            float em_n[PF];
            #pragma unroll
            for (int j = 0; j < PF; ++j) {
                int tf = t0 + PF + j;
                em_n[j] = (act && tf < TLEN) ? fb[tf * KS + lane] : -INFINITY;
            }
            #pragma unroll
            for (int j = 0; j < PF; ++j) fstep(em[j]);
            #pragma unroll
            for (int j = 0; j < PF; ++j) em[j] = em_n[j];
        }
        #pragma unroll
        for (int j = 0; j < 7; ++j) fstep(em[j]);

        float tstop = act ? trans[STOP_S * KS + lane] : NEGV;
        if (lane == STOP_S) tstop = NEGV;
        float z = alpha + tstop;
        float mz = z;
        #pragma unroll
        for (int off = 32; off; off >>= 1)
            mz = fmaxf(mz, __shfl_xor(mz, off, 64));
        float se = __expf(z - mz);
        #pragma unroll
        for (int off = 32; off; off >>= 1)
            se += __shfl_xor(se, off, 64);
        float logZ = mz + __logf(se);

        float g = 0.0f;
        for (int t = lane; t < TLEN; t += 64) {
            int tg = tb[t];
            int pg = (t == 0) ? START_S : tb[t - 1];
            g += fb[t * KS + tg] + trans[tg * KS + pg];
        }
        #pragma unroll
        for (int off = 32; off; off >>= 1)
            g += __shfl_xor(g, off, 64);
        g += trans[STOP_S * KS + tb[TLEN - 1]];

        if (lane == 0) out[b] = logZ - g;
    } else {
        // ====== VITERBI: max-only readlane scan + LDS-staged ballot chase ======
        const int b = blockIdx.x - BN;
        const float* fb = feats + (size_t)b * TLEN * KS;
        float* vw = vw_g + (size_t)b * TLEN * KS;

        float Trow[KS];   // masked trans[next=lane][p] — reference's exact add
        {
            const float* tr = trans + (act ? lane : 0) * KS;
            #pragma unroll
            for (int p = 0; p < KS; ++p) {
                float tv = act ? tr[p] : NEGV;
                if (lane == START_S) tv = NEGV;
                if (p == STOP_S)     tv = NEGV;
                Trow[p] = tv;
            }
        }

        float vit = (lane == START_S) ? 0.0f : NEGV;
        float lastB = 0.0f;

        // max-only core, readlane exchange: zero DS ops, zero compares.
        // 4 independent max chains (depth 12) + 2-level merge; fp max exact.
        auto vstep = [&](float emv, int t) {
            const float vp = vit;
            float m0 = -3.0e38f, m1 = -3.0e38f, m2 = -3.0e38f, m3 = -3.0e38f;
            #pragma unroll
            for (int g = 0; g < KS / 4; ++g) {
                float w0 = rlane(vp, 4 * g + 0) + Trow[4 * g + 0];
                float w1 = rlane(vp, 4 * g + 1) + Trow[4 * g + 1];
                float w2 = rlane(vp, 4 * g + 2) + Trow[4 * g + 2];
                float w3 = rlane(vp, 4 * g + 3) + Trow[4 * g + 3];
                m0 = fmaxf(m0, w0);
                m1 = fmaxf(m1, w1);
                m2 = fmaxf(m2, w2);
                m3 = fmaxf(m3, w3);
            }
            float B = fmaxf(fmaxf(m0, m1), fmaxf(m2, m3));  // pre-emission max
            if (act) vw[t * KS + lane] = B;      // fire-and-forget, coalesced
            lastB = B;
            vit = B + emv;                       // reference's exact add
        };

        float em[PF];
        #pragma unroll
        for (int j = 0; j < PF; ++j)
            em[j] = act ? fb[j * KS + lane] : 0.0f;
        for (int c = 0; c < 64; ++c) {           // 512 = 64*8 exactly
            const int t0 = c * PF;
            float em_n[PF];
            if (c < 63) {
                #pragma unroll
                for (int j = 0; j < PF; ++j)
                    em_n[j] = act ? fb[(t0 + PF + j) * KS + lane] : 0.0f;
            }
            #pragma unroll
            for (int j = 0; j < PF; ++j) vstep(em[j], t0 + j);
            if (c < 63) {
                #pragma unroll
                for (int j = 0; j < PF; ++j) em[j] = em_n[j];
            }
        }

        // drain B stores before re-reading them in the chase
        asm volatile("s_waitcnt vmcnt(0)" ::: "memory");

        // ---- bt-phase LDS layout (same-wave in-order DS) ----
        float* trans_sh = (float*)pool;                    //  9216 B
        float* Bch      = (float*)(pool + 9216);           //  3072 B (16 rows)
        float* Ech      = (float*)(pool + 12288);          //  3072 B (16 rows)
        unsigned char* path_sh = pool + 15360;             //   512 B

        // stage masked trans (row-major [next][prev]) — R0 bits
        for (int idx = lane; idx < KS * KS; idx += 64) {
            int n = idx / KS, p = idx - n * KS;
            float tv = trans[idx];
            if (n == START_S) tv = NEGV;
            if (p == STOP_S)  tv = NEGV;
            trans_sh[idx] = tv;
        }

        float tstop = act ? trans[STOP_S * KS + lane] : NEGV;
        if (lane == STOP_S) tstop = NEGV;
        float term = act ? (vit + tstop) : -3.0e38f;
        float bv = term;
        int   bidx = act ? lane : 9999;
        wargmax(bv, bidx);                       // terminal only (once)
        int tag = __builtin_amdgcn_readfirstlane(bidx);
        if (lane == 0) {
            out[BN + b] = bv;
            path_sh[TLEN - 1] = (unsigned char)tag;
        }

        // ---- chunked ballot chase: 32 chunks x 16 rows of B and e ----
        // tag_{t-1} = first p with fl(B_{t-1}[p]+e_{t-1}[p]) + T[tag,p]
        //             == B_t[tag]   (R0-validated exact semantics)
        float Bcur = lastB;                      // B_t row, lane p holds [p]
        const int ll = act ? lane : 0;           // clamp inactive-lane addresses
        for (int c = 31; c >= 0; --c) {
            float4 tb_[3], te_[3];
            const float4* bs4 = (const float4*)(vw + (size_t)c * 16 * KS);
            const float4* es4 = (const float4*)(fb + (size_t)c * 16 * KS);
            #pragma unroll
            for (int i = 0; i < 3; ++i) {
                tb_[i] = bs4[lane + 64 * i];
                te_[i] = es4[lane + 64 * i];
            }
            // in-order DS: previous chunk's chase reads precede these writes
            #pragma unroll
            for (int i = 0; i < 3; ++i) {
                ((float4*)Bch)[lane + 64 * i] = tb_[i];
                ((float4*)Ech)[lane + 64 * i] = te_[i];
            }
            int thi = c * 16 + 16; if (thi > TLEN - 1) thi = TLEN - 1;
            const int tlo = c * 16 + 1;
            for (int t = thi; t >= tlo; --t) {
                float Bv = Bch[((t - 1) & 15) * KS + ll];   // B_{t-1}[lane]
                float Ev = Ech[((t - 1) & 15) * KS + ll];   // e_{t-1}[lane]
                float tr = trans_sh[tag * KS + ll];         // T[tag, lane]
                float v  = Bv + Ev;                         // scan's exact vit
                float sc = act ? (v + tr) : -INFINITY;      // scan's exact cand
                float bt = rlane(Bcur, tag);                // B_t[tag]
                unsigned long long mk =
                    __ballot(sc == bt) & ((1ULL << KS) - 1ULL);
                tag = __builtin_amdgcn_readfirstlane((int)__builtin_ctzll(mk));
                if (lane == 0) path_sh[t - 1] = (unsigned char)tag;
                Bcur = Bv;
            }
        }
        __syncthreads();   // single wave: drains LDS before the read-back
        float* pout = out + 2 * BN + (size_t)b * TLEN;
        for (int t = lane; t < TLEN; t += 64)
            pout[t] = (float)path_sh[t];
    }
}

extern "C" void kernel_launch(void* const* d_in, const int* in_sizes, int n_in,
                              void* d_out, int out_size, void* d_ws, size_t ws_size,
                              hipStream_t stream) {
    const float* feats = (const float*)d_in[0];
    const float* trans = (const float*)d_in[1];
    const int*   tags  = (const int*)d_in[2];
    float*       out   = (float*)d_out;
    (void)in_sizes; (void)n_in; (void)out_size; (void)ws_size;

    // workspace: [B, T, K] f32 B-rows = 100.7 MB (ws_size >= this, verified R0)
    crf17<<<dim3(2 * BN), dim3(64), 0, stream>>>(feats, trans, tags, out,
                                                 (float*)d_ws);
}

// Round 11
// 401.496 us; speedup vs baseline: 1.0112x; 1.0112x over previous
//
#include <hip/hip_runtime.h>
#include <math.h>

#define KS 48
#define TLEN 512
#define BN 1024
#define START_S 46
#define STOP_S 47
#define NEGV -10000.0f
#define PF 8   // emission prefetch depth

typedef float v2f __attribute__((ext_vector_type(2)));

__device__ __forceinline__ float bcast_lane0(float v) {
    return __builtin_bit_cast(float, __builtin_amdgcn_readfirstlane(__builtin_bit_cast(int, v)));
}
__device__ __forceinline__ float rlane(float v, int k) {
    return __builtin_bit_cast(float, __builtin_amdgcn_readlane(__builtin_bit_cast(int, v), k));
}

// wave argmax, first-index tie-break (terminal only; validated rounds 1-7)
__device__ __forceinline__ void wargmax(float& bv, int& bi) {
    #pragma unroll
    for (int off = 32; off; off >>= 1) {
        float ov = __shfl_xor(bv, off, 64);
        int   oi = __shfl_xor(bi, off, 64);
        if (ov > bv || (ov == bv && oi < bi)) { bv = ov; bi = oi; }
    }
}

// grid = 2048, 1-wave blocks (concurrent structure).
// ROUND-18: R10 falsified readlane on the max-only core (272->319): the LDS
// round-trip is this machine's cheapest 48-wide broadcast. Scan = R9 verbatim
// (empirical plateau after 7 mechanism probes; occupancy structurally capped
// at 2 waves/SIMD by 2048 serial scans). Remaining modelable gap: the chase's
// per-step tag-dependent trans_sh LDS read (~120cy of a ~190cy chain).
// Fix: transposed masked T in REGISTERS (lane p holds Tc[k]=T[k][p], 48 VGPR)
// + wave-uniform switch lookup (scalar jump, compile-time reg indices — no
// dynamic VGPR indexing, no scratch). trans_sh staging deleted (LDS 16K->8K).
// Chase chain ~190 -> ~60-80cy/step. Values identical: same masked T, same
// fl(fl(B+e)+T), same ballot equality + first-set-bit tie-break.
__global__ __launch_bounds__(64) void crf18(
    const float* __restrict__ feats,   // [B, T, K]
    const float* __restrict__ trans,   // [K, K]  trans[next, prev]
    const int*   __restrict__ tags,    // [B, T]
    float*       __restrict__ out,     // [B] nll | [B] path_score | [B*T] paths
    float*       __restrict__ vw_g)    // [B, T, K] pre-emission max rows B_t
{
    const int lane = threadIdx.x;
    const bool act = lane < KS;

    __shared__ __align__(16) unsigned char pool[8192];
    float* xbuf = (float*)pool;                    // scan phase: 256B exchange

    if (blockIdx.x < BN) {
        // ================= FORWARD (verbatim, absmax 0.0 for 10 rounds) ========
        const int b = blockIdx.x;
        const float* fb = feats + (size_t)b * TLEN * KS;
        const int*   tb = tags + (size_t)b * TLEN;

        float Erow[KS];   // exp(masked trans[next=lane][p]); exp(-10000)==0
        {
            const float* tr = trans + (act ? lane : 0) * KS;
            #pragma unroll
            for (int p = 0; p < KS; ++p) {
                float tv = act ? tr[p] : NEGV;
                if (lane == START_S) tv = NEGV;
                if (p == STOP_S)     tv = NEGV;
                Erow[p] = __expf(tv);
            }
        }
        float tstart = act ? trans[lane * KS + START_S] : NEGV;
        if (lane == START_S) tstart = NEGV;

        float alpha = (act ? fb[lane] : -INFINITY) + tstart;   // t=0 peeled, exact

        auto fstep = [&](float emv) {
            float s  = bcast_lane0(alpha);       // lane-0 alpha finite: valid shift
            float ue = __expf(alpha - s);        // -inf lanes -> 0
            xbuf[lane] = ue;                     // same-wave in-order LDS: no barrier
            const float4* uu = (const float4*)xbuf;
            v2f acc0 = {0.f, 0.f}, acc1 = {0.f, 0.f};
            #pragma unroll
            for (int g = 0; g < KS / 4; ++g) {
                float4 u = uu[g];
                v2f ua = {u.x, u.y}, ub = {u.z, u.w};
                v2f ea = {Erow[4 * g + 0], Erow[4 * g + 1]};
                v2f eb = {Erow[4 * g + 2], Erow[4 * g + 3]};
                acc0 = __builtin_elementwise_fma(ua, ea, acc0);
                acc1 = __builtin_elementwise_fma(ub, eb, acc1);
            }
            alpha = emv + s + __logf((acc0.x + acc0.y) + (acc1.x + acc1.y));
        };

        float em[PF];
        #pragma unroll
        for (int j = 0; j < PF; ++j)
            em[j] = act ? fb[(1 + j) * KS + lane] : -INFINITY;
        for (int c = 0; c < 63; ++c) {
            const int t0 = 1 + c * PF;
            float em_n[PF];
            #pragma unroll
            for (int j = 0; j < PF; ++j) {
                int tf = t0 + PF + j;
                em_n[j] = (act && tf < TLEN) ? fb[tf * KS + lane] : -INFINITY;
            }
            #pragma unroll
            for (int j = 0; j < PF; ++j) fstep(em[j]);
            #pragma unroll
            for (int j = 0; j < PF; ++j) em[j] = em_n[j];
        }
        #pragma unroll
        for (int j = 0; j < 7; ++j) fstep(em[j]);

        float tstop = act ? trans[STOP_S * KS + lane] : NEGV;
        if (lane == STOP_S) tstop = NEGV;
        float z = alpha + tstop;
        float mz = z;
        #pragma unroll
        for (int off = 32; off; off >>= 1)
            mz = fmaxf(mz, __shfl_xor(mz, off, 64));
        float se = __expf(z - mz);
        #pragma unroll
        for (int off = 32; off; off >>= 1)
            se += __shfl_xor(se, off, 64);
        float logZ = mz + __logf(se);

        float g = 0.0f;
        for (int t = lane; t < TLEN; t += 64) {
            int tg = tb[t];
            int pg = (t == 0) ? START_S : tb[t - 1];
            g += fb[t * KS + tg] + trans[tg * KS + pg];
        }
        #pragma unroll
        for (int off = 32; off; off >>= 1)
            g += __shfl_xor(g, off, 64);
        g += trans[STOP_S * KS + tb[TLEN - 1]];

        if (lane == 0) out[b] = logZ - g;
    } else {
        // ====== VITERBI: max-only scan (R9 verbatim) + register-T ballot chase =
        const int b = blockIdx.x - BN;
        const float* fb = feats + (size_t)b * TLEN * KS;
        float* vw = vw_g + (size_t)b * TLEN * KS;

        float Trow[KS];   // masked trans[next=lane][p] — reference's exact add
        {
            const float* tr = trans + (act ? lane : 0) * KS;
            #pragma unroll
            for (int p = 0; p < KS; ++p) {
                float tv = act ? tr[p] : NEGV;
                if (lane == START_S) tv = NEGV;
                if (p == STOP_S)     tv = NEGV;
                Trow[p] = tv;
            }
        }

        float vit = (lane == START_S) ? 0.0f : NEGV;
        float lastB = 0.0f;

        // R9's proven max-only core: zero compares, fp max exact.
        auto vstep = [&](float emv, int t) {
            xbuf[lane] = vit;                    // in-order LDS, no barrier
            const float4* ww = (const float4*)xbuf;
            v2f m0 = {-3.0e38f, -3.0e38f}, m1 = {-3.0e38f, -3.0e38f};
            #pragma unroll
            for (int g = 0; g < KS / 4; ++g) {
                float4 w = ww[g];
                v2f wa = {w.x, w.y}, wb = {w.z, w.w};
                v2f ta = {Trow[4 * g + 0], Trow[4 * g + 1]};
                v2f tc = {Trow[4 * g + 2], Trow[4 * g + 3]};
                m0 = __builtin_elementwise_max(m0, wa + ta);   // v_pk ops
                m1 = __builtin_elementwise_max(m1, wb + tc);
            }
            v2f mm = __builtin_elementwise_max(m0, m1);
            float B = fmaxf(mm.x, mm.y);         // pre-emission max row (exact)
            if (act) vw[t * KS + lane] = B;      // fire-and-forget, coalesced
            lastB = B;
            vit = B + emv;                       // reference's exact add
        };

        float em[PF];
        #pragma unroll
        for (int j = 0; j < PF; ++j)
            em[j] = act ? fb[j * KS + lane] : 0.0f;
        for (int c = 0; c < 64; ++c) {           // 512 = 64*8 exactly
            const int t0 = c * PF;
            float em_n[PF];
            if (c < 63) {
                #pragma unroll
                for (int j = 0; j < PF; ++j)
                    em_n[j] = act ? fb[(t0 + PF + j) * KS + lane] : 0.0f;
            }
            #pragma unroll
            for (int j = 0; j < PF; ++j) vstep(em[j], t0 + j);
            if (c < 63) {
                #pragma unroll
                for (int j = 0; j < PF; ++j) em[j] = em_n[j];
            }
        }

        // drain B stores before re-reading them in the chase
        asm volatile("s_waitcnt vmcnt(0)" ::: "memory");

        const int ll = act ? lane : 0;           // clamp inactive-lane addresses

        // ---- Tc: transposed masked T in registers: lane p holds T[k][p] ----
        float Tc[KS];
        #pragma unroll
        for (int k = 0; k < KS; ++k) {
            float tv = trans[k * KS + ll];       // coalesced per k (one-time)
            if (k == START_S || ll == STOP_S) tv = NEGV;
            Tc[k] = tv;
        }
        // wave-uniform tag -> scalar branch; all reg indices compile-time.
        auto tsel = [&](int tg) -> float {
            float tr;
            switch (tg) {
#define CSE(K) case K: tr = Tc[K]; break;
                CSE(0)  CSE(1)  CSE(2)  CSE(3)  CSE(4)  CSE(5)  CSE(6)  CSE(7)
                CSE(8)  CSE(9)  CSE(10) CSE(11) CSE(12) CSE(13) CSE(14) CSE(15)
                CSE(16) CSE(17) CSE(18) CSE(19) CSE(20) CSE(21) CSE(22) CSE(23)
                CSE(24) CSE(25) CSE(26) CSE(27) CSE(28) CSE(29) CSE(30) CSE(31)
                CSE(32) CSE(33) CSE(34) CSE(35) CSE(36) CSE(37) CSE(38) CSE(39)
                CSE(40) CSE(41) CSE(42) CSE(43) CSE(44) CSE(45) CSE(46) CSE(47)
#undef CSE
                default: tr = NEGV; break;
            }
            return tr;
        };

        // ---- bt-phase LDS layout (aliases xbuf; same-wave in-order DS) ----
        float* Bch = (float*)pool;                         // 3072 B (16 rows)
        float* Ech = (float*)(pool + 3072);                // 3072 B (16 rows)
        unsigned char* path_sh = pool + 6144;              //  512 B

        float tstop = act ? trans[STOP_S * KS + lane] : NEGV;
        if (lane == STOP_S) tstop = NEGV;
        float term = act ? (vit + tstop) : -3.0e38f;
        float bv = term;
        int   bidx = act ? lane : 9999;
        wargmax(bv, bidx);                       // terminal only (once)
        int tag = __builtin_amdgcn_readfirstlane(bidx);
        if (lane == 0) {
            out[BN + b] = bv;
            path_sh[TLEN - 1] = (unsigned char)tag;
        }

        float Bcur = lastB;                      // B_t row, lane p holds [p]

        // stage chunk c: rows c*16 .. c*16+15 of B and e into LDS
        auto stage = [&](int c) {
            float4 tb_[3], te_[3];
            const float4* bs4 = (const float4*)(vw + (size_t)c * 16 * KS);
            const float4* es4 = (const float4*)(fb + (size_t)c * 16 * KS);
            #pragma unroll
            for (int i = 0; i < 3; ++i) {
                tb_[i] = bs4[lane + 64 * i];
                te_[i] = es4[lane + 64 * i];
            }
            // in-order DS: previous chunk's chase reads precede these writes
            #pragma unroll
            for (int i = 0; i < 3; ++i) {
                ((float4*)Bch)[lane + 64 * i] = tb_[i];
                ((float4*)Ech)[lane + 64 * i] = te_[i];
            }
        };
        // one chase step: handles time t = tpos+1, emits tag at tpos
        auto cstep = [&](int slot, int tpos) {
            float Bv = Bch[slot * KS + ll];      // B_{t-1}[lane] (tag-indep)
            float Ev = Ech[slot * KS + ll];      // e_{t-1}[lane] (tag-indep)
            float tr = tsel(tag);                // T[tag][lane] from registers
            float v  = Bv + Ev;                  // scan's exact vit value
            float sc = act ? (v + tr) : -INFINITY;   // scan's exact candidate
            float bt = rlane(Bcur, tag);         // B_t[tag]
            unsigned long long mk =
                __ballot(sc == bt) & ((1ULL << KS) - 1ULL);
            tag = __builtin_amdgcn_readfirstlane((int)__builtin_ctzll(mk));
            if (lane == 0) path_sh[tpos] = (unsigned char)tag;
            Bcur = Bv;
        };

        // chunk 31 (rows 496..511): 15 steps, t = 511..497
        stage(31);
        #pragma unroll 5
        for (int s = 0; s < 15; ++s) cstep(14 - s, 510 - s);
        // chunks 30..0: 16 steps each, t = c*16+16 .. c*16+1
        for (int c = 30; c >= 0; --c) {
            stage(c);
            #pragma unroll 4
            for (int s = 0; s < 16; ++s) cstep(15 - s, c * 16 + 15 - s);
        }

        __syncthreads();   // single wave: drains LDS before the read-back
        float* pout = out + 2 * BN + (size_t)b * TLEN;
        for (int t = lane; t < TLEN; t += 64)
            pout[t] = (float)path_sh[t];
    }
}

extern "C" void kernel_launch(void* const* d_in, const int* in_sizes, int n_in,
                              void* d_out, int out_size, void* d_ws, size_t ws_size,
                              hipStream_t stream) {
    const float* feats = (const float*)d_in[0];
    const float* trans = (const float*)d_in[1];
    const int*   tags  = (const int*)d_in[2];
    float*       out   = (float*)d_out;
    (void)in_sizes; (void)n_in; (void)out_size; (void)ws_size;

    // workspace: [B, T, K] f32 B-rows = 100.7 MB (ws_size >= this, verified R0)
    crf18<<<dim3(2 * BN), dim3(64), 0, stream>>>(feats, trans, tags, out,
                                                 (float*)d_ws);
}

// Round 12
// 356.348 us; speedup vs baseline: 1.1393x; 1.1267x over previous
//
#include <hip/hip_runtime.h>
#include <math.h>

#define KS 48
#define TLEN 512
#define BN 1024
#define START_S 46
#define STOP_S 47
#define NEGV -10000.0f
#define PF 8   // emission prefetch depth

typedef float v2f __attribute__((ext_vector_type(2)));

__device__ __forceinline__ float bcast_lane0(float v) {
    return __builtin_bit_cast(float, __builtin_amdgcn_readfirstlane(__builtin_bit_cast(int, v)));
}
__device__ __forceinline__ float rlane(float v, int k) {
    return __builtin_bit_cast(float, __builtin_amdgcn_readlane(__builtin_bit_cast(int, v), k));
}

// wave argmax, first-index tie-break (terminal only; validated rounds 1-7)
__device__ __forceinline__ void wargmax(float& bv, int& bi) {
    #pragma unroll
    for (int off = 32; off; off >>= 1) {
        float ov = __shfl_xor(bv, off, 64);
        int   oi = __shfl_xor(bi, off, 64);
        if (ov > bv || (ov == bv && oi < bi)) { bv = ov; bi = oi; }
    }
}

// grid = 2048, 1-wave blocks (concurrent structure).
// ROUND-19: REVERT to the R9 best (272us kernel / 356us bench, absmax 0.0).
// R11's register-T switch chase regressed (+43us: scalar-branch tree beats
// pipelined ds_read never). Configuration summary of what's proven here:
//   scan   = max-only pk core (zero compares — the R9 win: compare/VCC chains
//            were the vit tree's 450cy/step excess), LDS float4 broadcast
//            exchange (cheapest 48-wide broadcast; readlane 2x falsified),
//            B-row f32 fire-and-forget store;
//   chase  = chunk-staged B/e rows in LDS + ballot+ctz recompute (exact
//            semantics validated R0; 150-170cy/step);
//   fwd    = untouched verbatim (absmax 0.0 x11 rounds).
__global__ __launch_bounds__(64) void crf16(
    const float* __restrict__ feats,   // [B, T, K]
    const float* __restrict__ trans,   // [K, K]  trans[next, prev]
    const int*   __restrict__ tags,    // [B, T]
    float*       __restrict__ out,     // [B] nll | [B] path_score | [B*T] paths
    float*       __restrict__ vw_g)    // [B, T, K] pre-emission max rows B_t
{
    const int lane = threadIdx.x;
    const bool act = lane < KS;

    __shared__ __align__(16) unsigned char pool[16384];
    float* xbuf = (float*)pool;                    // scan phase: 256B exchange

    if (blockIdx.x < BN) {
        // ================= FORWARD (verbatim, absmax 0.0 for 11 rounds) ========
        const int b = blockIdx.x;
        const float* fb = feats + (size_t)b * TLEN * KS;
        const int*   tb = tags + (size_t)b * TLEN;

        float Erow[KS];   // exp(masked trans[next=lane][p]); exp(-10000)==0
        {
            const float* tr = trans + (act ? lane : 0) * KS;
            #pragma unroll
            for (int p = 0; p < KS; ++p) {
                float tv = act ? tr[p] : NEGV;
                if (lane == START_S) tv = NEGV;
                if (p == STOP_S)     tv = NEGV;
                Erow[p] = __expf(tv);
            }
        }
        float tstart = act ? trans[lane * KS + START_S] : NEGV;
        if (lane == START_S) tstart = NEGV;

        float alpha = (act ? fb[lane] : -INFINITY) + tstart;   // t=0 peeled, exact

        auto fstep = [&](float emv) {
            float s  = bcast_lane0(alpha);       // lane-0 alpha finite: valid shift
            float ue = __expf(alpha - s);        // -inf lanes -> 0
            xbuf[lane] = ue;                     // same-wave in-order LDS: no barrier
            const float4* uu = (const float4*)xbuf;
            v2f acc0 = {0.f, 0.f}, acc1 = {0.f, 0.f};
            #pragma unroll
            for (int g = 0; g < KS / 4; ++g) {
                float4 u = uu[g];
                v2f ua = {u.x, u.y}, ub = {u.z, u.w};
                v2f ea = {Erow[4 * g + 0], Erow[4 * g + 1]};
                v2f eb = {Erow[4 * g + 2], Erow[4 * g + 3]};
                acc0 = __builtin_elementwise_fma(ua, ea, acc0);
                acc1 = __builtin_elementwise_fma(ub, eb, acc1);
            }
            alpha = emv + s + __logf((acc0.x + acc0.y) + (acc1.x + acc1.y));
        };

        float em[PF];
        #pragma unroll
        for (int j = 0; j < PF; ++j)
            em[j] = act ? fb[(1 + j) * KS + lane] : -INFINITY;
        for (int c = 0; c < 63; ++c) {
            const int t0 = 1 + c * PF;
            float em_n[PF];
            #pragma unroll
            for (int j = 0; j < PF; ++j) {
                int tf = t0 + PF + j;
                em_n[j] = (act && tf < TLEN) ? fb[tf * KS + lane] : -INFINITY;
            }
            #pragma unroll
            for (int j = 0; j < PF; ++j) fstep(em[j]);
            #pragma unroll
            for (int j = 0; j < PF; ++j) em[j] = em_n[j];
        }
        #pragma unroll
        for (int j = 0; j < 7; ++j) fstep(em[j]);

        float tstop = act ? trans[STOP_S * KS + lane] : NEGV;
        if (lane == STOP_S) tstop = NEGV;
        float z = alpha + tstop;
        float mz = z;
        #pragma unroll
        for (int off = 32; off; off >>= 1)
            mz = fmaxf(mz, __shfl_xor(mz, off, 64));
        float se = __expf(z - mz);
        #pragma unroll
        for (int off = 32; off; off >>= 1)
            se += __shfl_xor(se, off, 64);
        float logZ = mz + __logf(se);

        float g = 0.0f;
        for (int t = lane; t < TLEN; t += 64) {
            int tg = tb[t];
            int pg = (t == 0) ? START_S : tb[t - 1];
            g += fb[t * KS + tg] + trans[tg * KS + pg];
        }
        #pragma unroll
        for (int off = 32; off; off >>= 1)
            g += __shfl_xor(g, off, 64);
        g += trans[STOP_S * KS + tb[TLEN - 1]];

        if (lane == 0) out[b] = logZ - g;
    } else {
        // ====== VITERBI: max-only scan (B-row store) + LDS-staged ballot chase =
        const int b = blockIdx.x - BN;
        const float* fb = feats + (size_t)b * TLEN * KS;
        float* vw = vw_g + (size_t)b * TLEN * KS;

        float Trow[KS];   // masked trans[next=lane][p] — reference's exact add
        {
            const float* tr = trans + (act ? lane : 0) * KS;
            #pragma unroll
            for (int p = 0; p < KS; ++p) {
                float tv = act ? tr[p] : NEGV;
                if (lane == START_S) tv = NEGV;
                if (p == STOP_S)     tv = NEGV;
                Trow[p] = tv;
            }
        }

        float vit = (lane == START_S) ? 0.0f : NEGV;
        float lastB = 0.0f;

        // max-only core: zero compares, fp max exact.
        auto vstep = [&](float emv, int t) {
            xbuf[lane] = vit;                    // in-order LDS, no barrier
            const float4* ww = (const float4*)xbuf;
            v2f m0 = {-3.0e38f, -3.0e38f}, m1 = {-3.0e38f, -3.0e38f};
            #pragma unroll
            for (int g = 0; g < KS / 4; ++g) {
                float4 w = ww[g];
                v2f wa = {w.x, w.y}, wb = {w.z, w.w};
                v2f ta = {Trow[4 * g + 0], Trow[4 * g + 1]};
                v2f tc = {Trow[4 * g + 2], Trow[4 * g + 3]};
                m0 = __builtin_elementwise_max(m0, wa + ta);   // v_pk ops
                m1 = __builtin_elementwise_max(m1, wb + tc);
            }
            v2f mm = __builtin_elementwise_max(m0, m1);
            float B = fmaxf(mm.x, mm.y);         // pre-emission max row (exact)
            if (act) vw[t * KS + lane] = B;      // fire-and-forget, coalesced
            lastB = B;
            vit = B + emv;                       // reference's exact add
        };

        float em[PF];
        #pragma unroll
        for (int j = 0; j < PF; ++j)
            em[j] = act ? fb[j * KS + lane] : 0.0f;
        for (int c = 0; c < 64; ++c) {           // 512 = 64*8 exactly
            const int t0 = c * PF;
            float em_n[PF];
            if (c < 63) {
                #pragma unroll
                for (int j = 0; j < PF; ++j)
                    em_n[j] = act ? fb[(t0 + PF + j) * KS + lane] : 0.0f;
            }
            #pragma unroll
            for (int j = 0; j < PF; ++j) vstep(em[j], t0 + j);
            if (c < 63) {
                #pragma unroll
                for (int j = 0; j < PF; ++j) em[j] = em_n[j];
            }
        }

        // drain B stores before re-reading them in the chase
        asm volatile("s_waitcnt vmcnt(0)" ::: "memory");

        // ---- bt-phase LDS layout (aliases xbuf; same-wave in-order DS) ----
        float* trans_sh = (float*)pool;                    //  9216 B
        float* Bch      = (float*)(pool + 9216);           //  3072 B (16 rows)
        float* Ech      = (float*)(pool + 12288);          //  3072 B (16 rows)
        unsigned char* path_sh = pool + 15360;             //   512 B

        // stage masked trans (row-major [next][prev]) — R0 bits
        for (int idx = lane; idx < KS * KS; idx += 64) {
            int n = idx / KS, p = idx - n * KS;
            float tv = trans[idx];
            if (n == START_S) tv = NEGV;
            if (p == STOP_S)  tv = NEGV;
            trans_sh[idx] = tv;
        }

        float tstop = act ? trans[STOP_S * KS + lane] : NEGV;
        if (lane == STOP_S) tstop = NEGV;
        float term = act ? (vit + tstop) : -3.0e38f;
        float bv = term;
        int   bidx = act ? lane : 9999;
        wargmax(bv, bidx);                       // terminal only (once)
        int tag = __builtin_amdgcn_readfirstlane(bidx);
        if (lane == 0) {
            out[BN + b] = bv;
            path_sh[TLEN - 1] = (unsigned char)tag;
        }

        // ---- chunked ballot chase: 32 chunks x 16 rows of B and e ----
        // tag_{t-1} = first p with fl(B_{t-1}[p]+e_{t-1}[p]) + T[tag,p]
        //             == B_t[tag]   (R0-validated exact semantics)
        float Bcur = lastB;                      // B_t row, lane p holds [p]
        const int ll = act ? lane : 0;           // clamp inactive-lane addresses
        for (int c = 31; c >= 0; --c) {
            float4 tb_[3], te_[3];
            const float4* bs4 = (const float4*)(vw + (size_t)c * 16 * KS);
            const float4* es4 = (const float4*)(fb + (size_t)c * 16 * KS);
            #pragma unroll
            for (int i = 0; i < 3; ++i) {
                tb_[i] = bs4[lane + 64 * i];
                te_[i] = es4[lane + 64 * i];
            }
            // in-order DS: previous chunk's chase reads precede these writes
            #pragma unroll
            for (int i = 0; i < 3; ++i) {
                ((float4*)Bch)[lane + 64 * i] = tb_[i];
                ((float4*)Ech)[lane + 64 * i] = te_[i];
            }
            int thi = c * 16 + 16; if (thi > TLEN - 1) thi = TLEN - 1;
            const int tlo = c * 16 + 1;
            for (int t = thi; t >= tlo; --t) {
                float Bv = Bch[((t - 1) & 15) * KS + ll];   // B_{t-1}[lane]
                float Ev = Ech[((t - 1) & 15) * KS + ll];   // e_{t-1}[lane]
                float tr = trans_sh[tag * KS + ll];         // T[tag, lane]
                float v  = Bv + Ev;                         // scan's exact vit
                float sc = act ? (v + tr) : -INFINITY;      // scan's exact cand
                float bt = rlane(Bcur, tag);                // B_t[tag]
                unsigned long long mk =
                    __ballot(sc == bt) & ((1ULL << KS) - 1ULL);
                tag = __builtin_amdgcn_readfirstlane((int)__builtin_ctzll(mk));
                if (lane == 0) path_sh[t - 1] = (unsigned char)tag;
                Bcur = Bv;
            }
        }
        __syncthreads();   // single wave: drains LDS before the read-back
        float* pout = out + 2 * BN + (size_t)b * TLEN;
        for (int t = lane; t < TLEN; t += 64)
            pout[t] = (float)path_sh[t];
    }
}

extern "C" void kernel_launch(void* const* d_in, const int* in_sizes, int n_in,
                              void* d_out, int out_size, void* d_ws, size_t ws_size,
                              hipStream_t stream) {
    const float* feats = (const float*)d_in[0];
    const float* trans = (const float*)d_in[1];
    const int*   tags  = (const int*)d_in[2];
    float*       out   = (float*)d_out;
    (void)in_sizes; (void)n_in; (void)out_size; (void)ws_size;

    // workspace: [B, T, K] f32 B-rows = 100.7 MB (ws_size >= this, verified R0)
    crf16<<<dim3(2 * BN), dim3(64), 0, stream>>>(feats, trans, tags, out,
                                                 (float*)d_ws);
}